// Round 4
// baseline (3731.932 us; speedup 1.0000x reference)
//
#include <hip/hip_runtime.h>
#include <hip/hip_bf16.h>
#include <math.h>

// Problem constants (fixed by the reference)
constexpr int Bc = 128, Tc = 16, Lc = 196, Ec = 512, Hc = 1024, Vc = 32000;

typedef float f32x4_t __attribute__((ext_vector_type(4)));
typedef short s16x8_t __attribute__((ext_vector_type(8)));

__device__ __forceinline__ float sigmoidf_(float x) { return 1.0f / (1.0f + expf(-x)); }

__device__ __forceinline__ unsigned short bf16rn(float x) {
    union { float f; unsigned u; } v; v.f = x;
    unsigned r = v.u + 0x7fffu + ((v.u >> 16) & 1u);
    return (unsigned short)(r >> 16);
}
__device__ __forceinline__ float bf16tof(unsigned short h) {
    union { unsigned u; float f; } v; v.u = ((unsigned)h) << 16; return v.f;
}

// ---------------------------------------------------------------------------
// Batched weight prep: 8 transposes (src [K][N] f32 -> dhi/dlo [N][ldd]
// hi/lo bf16) + mean_a tail, all in ONE flat-grid dispatch. 256 threads.
// ---------------------------------------------------------------------------
struct TDesc {
    const float* src;
    unsigned short* dhi;
    unsigned short* dlo;
    int N, ldd, gx, base;
};
struct PrepP {
    TDesc d[8];
    int tblocks;             // total transpose blocks; mean tail follows
    const float* feats;
    float* mean_a;
};

__global__ __launch_bounds__(256)
void prep_multi(PrepP p)
{
    const int id = blockIdx.x;
    if (id >= p.tblocks) {
        // mean over L: b = idm>>1, e-chunk = idm&1
        int idm = id - p.tblocks;
        int b = idm >> 1;
        int e = (idm & 1) * 256 + threadIdx.x;
        const float* f = p.feats + ((size_t)b * Lc) * Ec + e;
        float s = 0.f;
        for (int l = 0; l < Lc; ++l) s += f[(size_t)l * Ec];
        p.mean_a[b * Ec + e] = s * (1.0f / Lc);
        return;
    }
    int di = 0;
#pragma unroll
    for (int i = 1; i < 8; ++i) if (id >= p.d[i].base) di = i;
    const TDesc d = p.d[di];
    const int lid = id - d.base;
    const int k0 = (lid % d.gx) * 32;
    const int n0 = (lid / d.gx) * 32;

    __shared__ float tile[32][33];
    const int tx = threadIdx.x & 31, ty = threadIdx.x >> 5;  // ty 0..7
#pragma unroll
    for (int i = 0; i < 4; ++i)
        tile[ty + i * 8][tx] = d.src[(size_t)(k0 + ty + i * 8) * d.N + n0 + tx];
    __syncthreads();
#pragma unroll
    for (int i = 0; i < 4; ++i) {
        int nl = ty + i * 8;
        float v = tile[tx][nl];
        unsigned short hi = bf16rn(v);
        unsigned short lo = bf16rn(v - bf16tof(hi));
        size_t off = (size_t)(n0 + nl) * d.ldd + k0 + tx;
        d.dhi[off] = hi;
        d.dlo[off] = lo;
    }
}

// ---------------------------------------------------------------------------
// Split-bf16 MFMA GEMM body (see round-1/2 comments). Virtual block coords
// allow co-scheduling two independent GEMMs in one dispatch (gemm_dual).
// ---------------------------------------------------------------------------
struct GemmP {
    const float* A;
    const unsigned short* Bhi;
    const unsigned short* Blo;
    float* C;
    const float* bias;
    long ldc, cslice;
    int lda, K, gx, gy, S;
};

__device__ __forceinline__ void gemm_body(char* smem, int bx, int by, int ksl, const GemmP& p)
{
    auto As_hi = (unsigned short (*)[128][32])(smem);
    auto As_lo = (unsigned short (*)[128][32])(smem + 16384);
    auto Bs_hi = (unsigned short (*)[128][32])(smem + 32768);
    auto Bs_lo = (unsigned short (*)[128][32])(smem + 49152);

    const int t = threadIdx.x;
    const int wave = t >> 6, lane = t & 63;
    const int wr = wave >> 1, wc = wave & 1;   // wave 2x2 within 128x128 tile
    const int lm = lane & 15, qd = lane >> 4;  // fragment coords
    const size_t m0 = (size_t)bx * 128;
    const size_t n0 = (size_t)by * 128;

    const int Ksl = p.K / p.S;        // caller guarantees %32==0, >=64
    const int kbase = ksl * Ksl;

    // staging assignment: thread -> (row = t>>1, k-half = (t&1)*16)
    const int srow = t >> 1;
    const int skh  = (t & 1) * 16;

    const float* Ap = p.A + (m0 + srow) * (size_t)p.lda + skh + kbase;
    const unsigned short* Bhp = p.Bhi + (n0 + srow) * (size_t)p.K + skh + kbase;
    const unsigned short* Blp = p.Blo + (n0 + srow) * (size_t)p.K + skh + kbase;

    const int nk = Ksl >> 5;
    float* Cp = p.C + (size_t)ksl * p.cslice;

    f32x4_t acc[4][4];
#pragma unroll
    for (int i = 0; i < 4; ++i)
#pragma unroll
        for (int j = 0; j < 4; ++j)
            acc[i][j] = (f32x4_t){0.f, 0.f, 0.f, 0.f};

    // register staging for the in-flight K-tile
    float av[16];
    s16x8_t sbh0, sbh1, sbl0, sbl1;

#define G_LOAD(k0_)                                              \
    do {                                                         \
        *(float4*)&av[0]  = *(const float4*)(Ap + (k0_));        \
        *(float4*)&av[4]  = *(const float4*)(Ap + (k0_) + 4);    \
        *(float4*)&av[8]  = *(const float4*)(Ap + (k0_) + 8);    \
        *(float4*)&av[12] = *(const float4*)(Ap + (k0_) + 12);   \
        sbh0 = *(const s16x8_t*)(Bhp + (k0_));                   \
        sbh1 = *(const s16x8_t*)(Bhp + (k0_) + 8);               \
        sbl0 = *(const s16x8_t*)(Blp + (k0_));                   \
        sbl1 = *(const s16x8_t*)(Blp + (k0_) + 8);               \
    } while (0)

#define LDS_STORE(buf_)                                          \
    do {                                                         \
        s16x8_t h0, h1, l0, l1;                                  \
        _Pragma("unroll")                                        \
        for (int i = 0; i < 8; ++i) {                            \
            unsigned short hi = bf16rn(av[i]);                   \
            h0[i] = (short)hi;                                   \
            l0[i] = (short)bf16rn(av[i] - bf16tof(hi));          \
        }                                                        \
        _Pragma("unroll")                                        \
        for (int i = 0; i < 8; ++i) {                            \
            unsigned short hi = bf16rn(av[8 + i]);               \
            h1[i] = (short)hi;                                   \
            l1[i] = (short)bf16rn(av[8 + i] - bf16tof(hi));      \
        }                                                        \
        *(s16x8_t*)&As_hi[buf_][srow][skh]     = h0;             \
        *(s16x8_t*)&As_hi[buf_][srow][skh + 8] = h1;             \
        *(s16x8_t*)&As_lo[buf_][srow][skh]     = l0;             \
        *(s16x8_t*)&As_lo[buf_][srow][skh + 8] = l1;             \
        *(s16x8_t*)&Bs_hi[buf_][srow][skh]     = sbh0;           \
        *(s16x8_t*)&Bs_hi[buf_][srow][skh + 8] = sbh1;           \
        *(s16x8_t*)&Bs_lo[buf_][srow][skh]     = sbl0;           \
        *(s16x8_t*)&Bs_lo[buf_][srow][skh + 8] = sbl1;           \
    } while (0)

    // prologue: tile 0 into LDS[0], tile 1 in flight in registers
    G_LOAD(0);
    LDS_STORE(0);
    if (nk > 1) G_LOAD(32);
    __syncthreads();

    for (int k = 0; k < nk; ++k) {
        const int cur = k & 1;
        // issue this tile's fragment reads first (lgkm in flight)
        s16x8_t ah[4], al[4], bh[4], bl[4];
#pragma unroll
        for (int mt = 0; mt < 4; ++mt) {
            ah[mt] = *(const s16x8_t*)&As_hi[cur][wr * 64 + mt * 16 + lm][qd * 8];
            al[mt] = *(const s16x8_t*)&As_lo[cur][wr * 64 + mt * 16 + lm][qd * 8];
        }
#pragma unroll
        for (int nt = 0; nt < 4; ++nt) {
            bh[nt] = *(const s16x8_t*)&Bs_hi[cur][wc * 64 + nt * 16 + lm][qd * 8];
            bl[nt] = *(const s16x8_t*)&Bs_lo[cur][wc * 64 + nt * 16 + lm][qd * 8];
        }
        // drain in-flight registers into the other LDS buffer, then issue
        // the next prefetch (2 tiles ahead) before the MFMA cluster
        if (k + 1 < nk) {
            LDS_STORE(cur ^ 1);
            if (k + 2 < nk) G_LOAD((k + 2) << 5);
        }
#pragma unroll
        for (int mt = 0; mt < 4; ++mt)
#pragma unroll
            for (int nt = 0; nt < 4; ++nt) {
                acc[mt][nt] = __builtin_amdgcn_mfma_f32_16x16x32_bf16(ah[mt], bh[nt], acc[mt][nt], 0, 0, 0);
                acc[mt][nt] = __builtin_amdgcn_mfma_f32_16x16x32_bf16(ah[mt], bl[nt], acc[mt][nt], 0, 0, 0);
                acc[mt][nt] = __builtin_amdgcn_mfma_f32_16x16x32_bf16(al[mt], bh[nt], acc[mt][nt], 0, 0, 0);
            }
        __syncthreads();
    }
#undef G_LOAD
#undef LDS_STORE

    // epilogue: C/D layout col=lane&15, row=qd*4+reg
#pragma unroll
    for (int nt = 0; nt < 4; ++nt) {
        size_t n = n0 + wc * 64 + nt * 16 + lm;
        float bs = p.bias ? p.bias[n] : 0.f;
#pragma unroll
        for (int mt = 0; mt < 4; ++mt) {
#pragma unroll
            for (int r = 0; r < 4; ++r) {
                size_t m = m0 + wr * 64 + mt * 16 + qd * 4 + r;
                Cp[(size_t)m * p.ldc + n] = acc[mt][nt][r] + bs;
            }
        }
    }
}

__global__ __launch_bounds__(256)
void gemm_one(GemmP p)
{
    __shared__ __align__(16) char smem[65536];
    gemm_body(smem, blockIdx.x, blockIdx.y, blockIdx.z, p);
}

// Two independent GEMMs in one dispatch (flat grid = nA + nB blocks).
__global__ __launch_bounds__(256)
void gemm_dual(GemmP a, GemmP b)
{
    __shared__ __align__(16) char smem[65536];
    int id = blockIdx.x;
    const int na = a.gx * a.gy * a.S;
    if (id < na) {
        int by = id % a.gy; int bx = (id / a.gy) % a.gx; int kz = id / (a.gy * a.gx);
        gemm_body(smem, bx, by, kz, a);
    } else {
        id -= na;
        int by = id % b.gy; int bx = (id / b.gy) % b.gx; int kz = id / (b.gy * b.gx);
        gemm_body(smem, bx, by, kz, b);
    }
}

// concat two f32 vectors
__global__ __launch_bounds__(256)
void concat2(const float* __restrict__ a, int na, const float* __restrict__ b, int nb,
             float* __restrict__ out)
{
    int i = blockIdx.x * 256 + threadIdx.x;
    if (i < na) out[i] = a[i];
    else if (i < na + nb) out[i] = b[i - na];
}

// mean over L (fallback path): grid=(B, E/256)
__global__ __launch_bounds__(256)
void mean_kernel(const float* __restrict__ feats, float* __restrict__ mean_a)
{
    int b = blockIdx.x;
    int e = blockIdx.y * 256 + threadIdx.x;
    const float* f = feats + ((size_t)b * Lc) * Ec + e;
    float s = 0.f;
    for (int l = 0; l < Lc; ++l) s += f[(size_t)l * Ec];
    mean_a[b * Ec + e] = s * (1.0f / Lc);
}

// ---------------------------------------------------------------------------
// Setup: write emb slices of ALL per-t xcat buffers (caption is static) and
// the h-slice of xcat[0] (from h0 in hc). One flat-grid dispatch.
// blocks [0, Tc*Bc*2): emb; blocks [Tc*Bc*2, +Bc*4): h0 copy. 256 thr.
// ---------------------------------------------------------------------------
__global__ __launch_bounds__(256)
void xemb_h0(const int* __restrict__ caption, const float* __restrict__ emb,
             const float* __restrict__ hc, float* __restrict__ xcat)
{
    const int nemb = Tc * Bc * 2;
    int id = blockIdx.x;
    if (id < nemb) {
        int t = id >> 8;                 // Bc*2 = 256 blocks per t
        int r = id & 255;
        int b = r >> 1;
        int j = (r & 1) * 256 + threadIdx.x;   // 0..511
        int tok = caption[b * Tc + t];
        xcat[(size_t)t * Bc * 2048 + (size_t)b * 2048 + 512 + j] = emb[(size_t)tok * Ec + j];
    } else {
        int idx = (id - nemb) * 256 + threadIdx.x;   // 0 .. Bc*1024-1
        int b = idx >> 10;
        int j = idx & 1023;
        xcat[(size_t)b * 2048 + 1024 + j] = hc[(size_t)b * 2048 + j];
    }
}

// ---------------------------------------------------------------------------
// Combined dispatch (1024 thr):
//   blocks [0, nsmv): softmax over V for out[b, t, :]
//   blocks [nsmv, ...): attz for step tn — per-b: q/sb from split-K partials,
//     e scores, softmax over L (LDS), z = alpha·feats, z*sigmoid(sb) written
//     straight into the z-slice of xcat_t. Replaces att+softmax_L+z+zxcat.
// ---------------------------------------------------------------------------
__global__ __launch_bounds__(1024)
void smv_attz(float* __restrict__ out, int t, int nsmv,
              const float* __restrict__ qp, long qstride,
              const float* __restrict__ b_a, const float* __restrict__ b_beta,
              const float* __restrict__ keys,
              const float* __restrict__ V_a, const float* __restrict__ b_va,
              const float* __restrict__ feats, float* __restrict__ xcat_t)
{
    __shared__ float red[1024];
    const int tid = threadIdx.x;
    if (blockIdx.x < (unsigned)nsmv) {
        int b = blockIdx.x;
        float* p = out + ((size_t)b * Tc + t) * (size_t)Vc;
        float m = -1e30f;
        for (int v = tid; v < Vc; v += 1024) m = fmaxf(m, p[v]);
        red[tid] = m; __syncthreads();
        for (int s = 512; s > 0; s >>= 1) { if (tid < s) red[tid] = fmaxf(red[tid], red[tid + s]); __syncthreads(); }
        m = red[0]; __syncthreads();
        float sum = 0.f;
        for (int v = tid; v < Vc; v += 1024) sum += expf(p[v] - m);
        red[tid] = sum; __syncthreads();
        for (int s = 512; s > 0; s >>= 1) { if (tid < s) red[tid] += red[tid + s]; __syncthreads(); }
        float inv = 1.0f / red[0];
        for (int v = tid; v < Vc; v += 1024) p[v] = expf(p[v] - m) * inv;
        return;
    }
    // ---------------- attz ----------------
    __shared__ float q_lds[Hc];
    __shared__ float va_lds[Hc];
    __shared__ float sb_lds[Ec];
    __shared__ float e_sm[256];
    __shared__ float alpha[Lc];
    const int b = blockIdx.x - nsmv;
    const float* q0 = qp + (size_t)b * 1536;
    q_lds[tid] = b_a[tid] + q0[tid] + q0[qstride + tid] + q0[2 * qstride + tid] + q0[3 * qstride + tid];
    va_lds[tid] = V_a[tid];
    if (tid < Ec) {
        const float* qs = q0 + 1024 + tid;
        sb_lds[tid] = b_beta[tid] + qs[0] + qs[qstride] + qs[2 * qstride] + qs[3 * qstride];
    }
    __syncthreads();
    // e scores: wave w handles l = w, w+16, ...
    {
        int wave = tid >> 6, lane = tid & 63;
        float bva = b_va[0];
        for (int l = wave; l < Lc; l += 16) {
            const float* kp = keys + ((size_t)b * Lc + l) * Hc;
            float s = 0.f;
            for (int h = lane; h < Hc; h += 64)
                s = fmaf(fmaxf(q_lds[h] + kp[h], 0.f), va_lds[h], s);
#pragma unroll
            for (int off = 32; off > 0; off >>= 1) s += __shfl_down(s, off);
            if (lane == 0) e_sm[l] = s + bva;
        }
    }
    __syncthreads();
    // softmax over L
    float ev = (tid < Lc) ? e_sm[tid] : -1e30f;
    red[tid] = ev; __syncthreads();
    for (int s = 512; s > 0; s >>= 1) { if (tid < s) red[tid] = fmaxf(red[tid], red[tid + s]); __syncthreads(); }
    float m = red[0]; __syncthreads();
    float ex = (tid < Lc) ? expf(ev - m) : 0.f;
    red[tid] = ex; __syncthreads();
    for (int s = 512; s > 0; s >>= 1) { if (tid < s) red[tid] += red[tid + s]; __syncthreads(); }
    if (tid < Lc) alpha[tid] = ex / red[0];
    __syncthreads();
    // z + beta-gate -> xcat z-slice
    if (tid < Ec) {
        const float* f = feats + ((size_t)b * Lc) * Ec + tid;
        float s = 0.f;
        for (int l = 0; l < Lc; ++l) s = fmaf(alpha[l], f[(size_t)l * Ec], s);
        xcat_t[(size_t)b * 2048 + tid] = s * sigmoidf_(sb_lds[tid]);
    }
}

// LSTM elementwise over 4 split-K gate partials + bias; writes h into hc and
// (optionally) into the h-slice of next step's xcat. grid=B*H/256
__global__ __launch_bounds__(256)
void lstm_elem_sk(const float* __restrict__ gp, long gstride,
                  const float* __restrict__ b_lstm,
                  float* __restrict__ hbase, float* __restrict__ cbase, int ld,
                  float* __restrict__ xh)
{
    int idx = blockIdx.x * 256 + threadIdx.x;
    int b = idx >> 10;
    int j = idx & (Hc - 1);
    float gi = b_lstm[j], gf = b_lstm[Hc + j], gg = b_lstm[2 * Hc + j], go = b_lstm[3 * Hc + j];
#pragma unroll
    for (int s = 0; s < 4; ++s) {
        const float* g = gp + (size_t)s * gstride + (size_t)b * 4 * Hc;
        gi += g[j]; gf += g[Hc + j]; gg += g[2 * Hc + j]; go += g[3 * Hc + j];
    }
    float* cp = cbase + (size_t)b * ld + j;
    float cn = sigmoidf_(gf) * (*cp) + sigmoidf_(gi) * tanhf(gg);
    *cp = cn;
    float hn = sigmoidf_(go) * tanhf(cn);
    hbase[(size_t)b * ld + j] = hn;
    if (xh) xh[(size_t)b * 2048 + 1024 + j] = hn;
}

// ---------------------------------------------------------------------------
// Legacy helpers (fallback path only)
// ---------------------------------------------------------------------------
__global__ __launch_bounds__(1024)
void softmax_V(float* __restrict__ out, int t)
{
    int b = blockIdx.x;
    float* p = out + ((size_t)b * Tc + t) * (size_t)Vc;
    __shared__ float red[1024];
    int tid = threadIdx.x;
    float m = -1e30f;
    for (int v = tid; v < Vc; v += 1024) m = fmaxf(m, p[v]);
    red[tid] = m; __syncthreads();
    for (int s = 512; s > 0; s >>= 1) { if (tid < s) red[tid] = fmaxf(red[tid], red[tid + s]); __syncthreads(); }
    m = red[0]; __syncthreads();
    float sum = 0.f;
    for (int v = tid; v < Vc; v += 1024) sum += expf(p[v] - m);
    red[tid] = sum; __syncthreads();
    for (int s = 512; s > 0; s >>= 1) { if (tid < s) red[tid] += red[tid + s]; __syncthreads(); }
    float inv = 1.0f / red[0];
    for (int v = tid; v < Vc; v += 1024) p[v] = expf(p[v] - m) * inv;
}

__global__ __launch_bounds__(256)
void att_scores(const float* __restrict__ q, int ldq, const float* __restrict__ keys,
                const float* __restrict__ V_a, const float* __restrict__ b_va,
                float* __restrict__ e)
{
    int pair = blockIdx.x * 4 + (threadIdx.x >> 6);
    int lane = threadIdx.x & 63;
    int b = pair / Lc;
    const float* qp = q + (size_t)b * ldq;
    const float* kp = keys + (size_t)pair * Hc;
    float s = 0.f;
    for (int h = lane; h < Hc; h += 64)
        s = fmaf(fmaxf(qp[h] + kp[h], 0.f), V_a[h], s);
#pragma unroll
    for (int off = 32; off > 0; off >>= 1) s += __shfl_down(s, off);
    if (lane == 0) e[pair] = s + b_va[0];
}

__global__ __launch_bounds__(256)
void softmax_L(float* __restrict__ e)
{
    int b = blockIdx.x;
    float* p = e + b * Lc;
    __shared__ float red[256];
    int tid = threadIdx.x;
    float m = -1e30f;
    if (tid < Lc) m = p[tid];
    red[tid] = m; __syncthreads();
    for (int s = 128; s > 0; s >>= 1) { if (tid < s) red[tid] = fmaxf(red[tid], red[tid + s]); __syncthreads(); }
    m = red[0]; __syncthreads();
    float ex = 0.f;
    if (tid < Lc) ex = expf(p[tid] - m);
    red[tid] = ex; __syncthreads();
    for (int s = 128; s > 0; s >>= 1) { if (tid < s) red[tid] += red[tid + s]; __syncthreads(); }
    if (tid < Lc) p[tid] = ex / red[0];
}

__global__ __launch_bounds__(256)
void z_kernel(const float* __restrict__ alpha, const float* __restrict__ feats,
              float* __restrict__ z)
{
    int b = blockIdx.x;
    int e = blockIdx.y * 256 + threadIdx.x;
    const float* f = feats + ((size_t)b * Lc) * Ec + e;
    const float* a = alpha + b * Lc;
    float s = 0.f;
    for (int l = 0; l < Lc; ++l) s = fmaf(a[l], f[(size_t)l * Ec], s);
    z[b * Ec + e] = s;
}

__global__ __launch_bounds__(256)
void ctx_build(const float* __restrict__ z, const float* __restrict__ sb,
               const int* __restrict__ caption, const float* __restrict__ emb,
               float* __restrict__ ctx, int t)
{
    int b = blockIdx.x;
    int j = blockIdx.y * 256 + threadIdx.x;
    float v;
    if (j < Ec) {
        v = z[b * Ec + j] * sigmoidf_(sb[b * Ec + j]);
    } else {
        int tok = caption[b * Tc + t];
        v = emb[(size_t)tok * Ec + (j - Ec)];
    }
    ctx[b * (2 * Ec) + j] = v;
}

__global__ __launch_bounds__(256)
void lstm_elem(const float* __restrict__ gates, float* __restrict__ hbase,
               float* __restrict__ cbase, int ld)
{
    int idx = blockIdx.x * 256 + threadIdx.x;
    int b = idx >> 10;
    int j = idx & (Hc - 1);
    const float* g = gates + (size_t)b * 4 * Hc;
    float gi = g[j], gf = g[Hc + j], gg = g[2 * Hc + j], go = g[3 * Hc + j];
    float* cp = cbase + (size_t)b * ld + j;
    float* hp = hbase + (size_t)b * ld + j;
    float cn = sigmoidf_(gf) * (*cp) + sigmoidf_(gi) * tanhf(gg);
    *cp = cn;
    *hp = sigmoidf_(go) * tanhf(cn);
}

__global__ __launch_bounds__(256)
void gemm_f32(const float* __restrict__ A, int lda,
              const float* __restrict__ Bm, int ldb,
              float* __restrict__ C, int ldc,
              const float* __restrict__ bias,
              int K, int accumulate)
{
    __shared__ __align__(16) float As[16][68];
    __shared__ __align__(16) float Bs[16][68];
    const int t  = threadIdx.x;
    const int tx = t & 15;
    const int ty = t >> 4;
    const size_t m0 = (size_t)blockIdx.x * 64;
    const size_t n0 = (size_t)blockIdx.y * 64;
    const int arow = t >> 2;
    const int acol = (t & 3) << 2;
    const int brow = t >> 4;
    const int bcol = (t & 15) << 2;
    const float* Aptr = A + (m0 + arow) * (size_t)lda + acol;
    const float* Bptr = Bm + (size_t)brow * ldb + n0 + bcol;
    float acc[4][4] = {};
    for (int k0 = 0; k0 < K; k0 += 16) {
        float4 av = *reinterpret_cast<const float4*>(Aptr + k0);
        float4 bv = *reinterpret_cast<const float4*>(Bptr + (size_t)k0 * ldb);
        As[acol + 0][arow] = av.x;
        As[acol + 1][arow] = av.y;
        As[acol + 2][arow] = av.z;
        As[acol + 3][arow] = av.w;
        *reinterpret_cast<float4*>(&Bs[brow][bcol]) = bv;
        __syncthreads();
#pragma unroll
        for (int k = 0; k < 16; ++k) {
            float4 a4 = *reinterpret_cast<const float4*>(&As[k][ty << 2]);
            float4 b4 = *reinterpret_cast<const float4*>(&Bs[k][tx << 2]);
            float aa[4] = {a4.x, a4.y, a4.z, a4.w};
            float bb[4] = {b4.x, b4.y, b4.z, b4.w};
#pragma unroll
            for (int i = 0; i < 4; ++i)
#pragma unroll
                for (int j = 0; j < 4; ++j)
                    acc[i][j] = fmaf(aa[i], bb[j], acc[i][j]);
        }
        __syncthreads();
    }
    float4 bv4 = {0.f, 0.f, 0.f, 0.f};
    if (bias) bv4 = *reinterpret_cast<const float4*>(&bias[n0 + (tx << 2)]);
#pragma unroll
    for (int i = 0; i < 4; ++i) {
        size_t off = (m0 + (size_t)(ty << 2) + i) * (size_t)ldc + n0 + (tx << 2);
        float4 o;
        o.x = acc[i][0] + bv4.x;
        o.y = acc[i][1] + bv4.y;
        o.z = acc[i][2] + bv4.z;
        o.w = acc[i][3] + bv4.w;
        if (accumulate) {
            float4 prev = *reinterpret_cast<const float4*>(&C[off]);
            o.x += prev.x; o.y += prev.y; o.z += prev.z; o.w += prev.w;
        }
        *reinterpret_cast<float4*>(&C[off]) = o;
    }
}

extern "C" void kernel_launch(void* const* d_in, const int* in_sizes, int n_in,
                              void* d_out, int out_size, void* d_ws, size_t ws_size,
                              hipStream_t stream)
{
    const int*   caption  = (const int*)  d_in[0];
    const float* feats    = (const float*)d_in[1];
    const float* emb      = (const float*)d_in[2];
    const float* W_init_h = (const float*)d_in[3];
    const float* b_init_h = (const float*)d_in[4];
    const float* W_init_c = (const float*)d_in[5];
    const float* b_init_c = (const float*)d_in[6];
    const float* W_a      = (const float*)d_in[7];
    const float* b_a      = (const float*)d_in[8];
    const float* U_a      = (const float*)d_in[9];
    const float* b_ua     = (const float*)d_in[10];
    const float* V_a      = (const float*)d_in[11];
    const float* b_va     = (const float*)d_in[12];
    const float* W_beta   = (const float*)d_in[13];
    const float* b_beta   = (const float*)d_in[14];
    const float* W_lstm   = (const float*)d_in[15];
    const float* U_lstm   = (const float*)d_in[16];
    const float* b_lstm   = (const float*)d_in[17];
    const float* W_out    = (const float*)d_in[18];
    const float* b_out    = (const float*)d_in[19];
    float* out = (float*)d_out;

    dim3 blk(256);

    // ---------------- fast-path workspace layout (bytes) ----------------
    char* base = (char*)d_ws;
    size_t off = 0;
    auto alloc = [&](size_t bytes) { char* p = base + off; off = (off + bytes + 15) & ~(size_t)15; return p; };

    float* keys      = (float*)alloc((size_t)Bc * Lc * Hc * 4);
    float* hc        = (float*)alloc((size_t)Bc * 2048 * 4);      // h | c per row
    float* qsb_part  = (float*)alloc((size_t)4 * Bc * 1536 * 4);  // 4 split-K partials of [q|sb]
    float* xcat      = (float*)alloc((size_t)Tc * Bc * 2048 * 4); // per-t [z*sig | emb | h]
    float* gate_part = (float*)alloc((size_t)4 * Bc * 4 * Hc * 4);// 4 split-K partials of gates
    float* mean_a    = (float*)alloc((size_t)Bc * Ec * 4);
    float* bcat_i    = (float*)alloc(2048 * 4);
    unsigned short* Wout_hi  = (unsigned short*)alloc((size_t)Vc * Hc * 2);
    unsigned short* Wout_lo  = (unsigned short*)alloc((size_t)Vc * Hc * 2);
    unsigned short* Wg_hi    = (unsigned short*)alloc((size_t)4096 * 2048 * 2);
    unsigned short* Wg_lo    = (unsigned short*)alloc((size_t)4096 * 2048 * 2);
    unsigned short* Wqsb_hi  = (unsigned short*)alloc((size_t)1536 * 1024 * 2);
    unsigned short* Wqsb_lo  = (unsigned short*)alloc((size_t)1536 * 1024 * 2);
    unsigned short* Ua_hi    = (unsigned short*)alloc((size_t)1024 * 512 * 2);
    unsigned short* Ua_lo    = (unsigned short*)alloc((size_t)1024 * 512 * 2);
    unsigned short* Wini_hi  = (unsigned short*)alloc((size_t)2048 * 512 * 2);
    unsigned short* Wini_lo  = (unsigned short*)alloc((size_t)2048 * 512 * 2);
    const size_t need_fast = off;

    const long QSTRIDE = (long)Bc * 1536;
    const long GSTRIDE = (long)Bc * 4 * Hc;
    const size_t XSLICE = (size_t)Bc * 2048;

    if (ws_size >= need_fast) {
        // ================= fast path: split-bf16 MFMA =================
        PrepP pp;
        int pb = 0;
        auto addT = [&](const float* src, int N, unsigned short* dhi, unsigned short* dlo,
                        int ldd, int gx, int gy, int slot) {
            pp.d[slot] = TDesc{src, dhi, dlo, N, ldd, gx, pb};
            pb += gx * gy;
        };
        addT(W_out,    Vc,   Wout_hi, Wout_lo, 1024, 32, 1000, 0);  // biggest first
        addT(W_lstm,   4096, Wg_hi,   Wg_lo,   2048, 32, 128, 1);
        addT(U_lstm,   4096, Wg_hi + 1024, Wg_lo + 1024, 2048, 32, 128, 2);
        addT(W_a,      1024, Wqsb_hi, Wqsb_lo, 1024, 32, 32, 3);
        addT(W_beta,   512,  Wqsb_hi + (size_t)1024 * 1024, Wqsb_lo + (size_t)1024 * 1024, 1024, 32, 16, 4);
        addT(U_a,      1024, Ua_hi,   Ua_lo,   512, 16, 32, 5);
        addT(W_init_h, 1024, Wini_hi, Wini_lo, 512, 16, 32, 6);
        addT(W_init_c, 1024, Wini_hi + (size_t)1024 * 512, Wini_lo + (size_t)1024 * 512, 512, 16, 32, 7);
        pp.tblocks = pb;
        pp.feats = feats;
        pp.mean_a = mean_a;
        prep_multi<<<dim3(pb + 256), blk, 0, stream>>>(pp);
        concat2<<<dim3(8), blk, 0, stream>>>(b_init_h, 1024, b_init_c, 1024, bcat_i);

        auto mkg = [](const float* A, int lda, const unsigned short* bh, const unsigned short* bl,
                      float* C, long ldc, const float* bias, int K, long cslice,
                      int gx, int gy, int S) {
            GemmP p; p.A = A; p.lda = lda; p.Bhi = bh; p.Blo = bl; p.C = C; p.ldc = ldc;
            p.bias = bias; p.K = K; p.cslice = cslice; p.gx = gx; p.gy = gy; p.S = S; return p;
        };
        GemmP g_init = mkg(mean_a, Ec, Wini_hi, Wini_lo, hc, 2048, bcat_i, 512, 0, 1, 16, 1);
        GemmP g_keys = mkg(feats, Ec, Ua_hi, Ua_lo, keys, Hc, b_ua, 512, 0, 196, 8, 1);
        GemmP g_qsb  = mkg(hc, 2048, Wqsb_hi, Wqsb_lo, qsb_part, 1536, nullptr, 1024, QSTRIDE, 1, 12, 4);

        // ---- setup ----
        gemm_one<<<dim3(1, 16, 1), blk, 0, stream>>>(g_init);
        xemb_h0<<<dim3(Tc * Bc * 2 + Bc * 4), blk, 0, stream>>>(caption, emb, hc, xcat);
        gemm_dual<<<dim3(196 * 8 + 48), blk, 0, stream>>>(g_keys, g_qsb);
        // attz(0): z-slice of xcat[0]  (no smv blocks)
        smv_attz<<<dim3(Bc), dim3(1024), 0, stream>>>(out, 0, 0, qsb_part, QSTRIDE, b_a, b_beta,
                                                      keys, V_a, b_va, feats, xcat);

        // ---- time steps: gate -> lstm -> {wout || qsb(t+1)} -> {smV || attz(t+1)} ----
        for (int t = 0; t < Tc; ++t) {
            GemmP g_gate = mkg(xcat + (size_t)t * XSLICE, 2048, Wg_hi, Wg_lo, gate_part, 4096, nullptr, 2048, GSTRIDE, 1, 32, 4);
            gemm_one<<<dim3(1, 32, 4), blk, 0, stream>>>(g_gate);
            float* xh = (t < Tc - 1) ? xcat + (size_t)(t + 1) * XSLICE : nullptr;
            lstm_elem_sk<<<dim3((Bc * Hc) / 256), blk, 0, stream>>>(gate_part, GSTRIDE, b_lstm, hc, hc + 1024, 2048, xh);
            GemmP g_wout = mkg(hc, 2048, Wout_hi, Wout_lo, out + (size_t)t * Vc, (long)Tc * Vc, b_out, 1024, 0, 1, 250, 1);
            if (t < Tc - 1)
                gemm_dual<<<dim3(250 + 48), blk, 0, stream>>>(g_wout, g_qsb);
            else
                gemm_one<<<dim3(1, 250, 1), blk, 0, stream>>>(g_wout);
            int natt = (t < Tc - 1) ? Bc : 0;
            smv_attz<<<dim3(128 + natt), dim3(1024), 0, stream>>>(out, t, 128, qsb_part, QSTRIDE, b_a, b_beta,
                                                                  keys, V_a, b_va, feats,
                                                                  xcat + (size_t)(t + 1) * XSLICE);
        }
        return;
    }

    // ================= legacy f32 fallback =================
    float* ws = (float*)d_ws;
    size_t foff = 0;
    float* l_keys  = ws + foff; foff += (size_t)Bc * Lc * Hc;
    float* l_h     = ws + foff; foff += (size_t)Bc * Hc;
    float* l_c     = ws + foff; foff += (size_t)Bc * Hc;
    float* l_q     = ws + foff; foff += (size_t)Bc * Hc;
    float* l_e     = ws + foff; foff += (size_t)Bc * Lc;
    float* l_sb    = ws + foff; foff += (size_t)Bc * Ec;
    float* l_z     = ws + foff; foff += (size_t)Bc * Ec;
    float* l_ctx   = ws + foff; foff += (size_t)Bc * 2 * Ec;
    float* l_gates = ws + foff; foff += (size_t)Bc * 4 * Hc;
    float* l_mean  = ws + foff; foff += (size_t)Bc * Ec;
    if (ws_size < foff * sizeof(float)) return;

    mean_kernel<<<dim3(Bc, 2), blk, 0, stream>>>(feats, l_mean);
    gemm_f32<<<dim3(Bc / 64, Hc / 64), blk, 0, stream>>>(l_mean, Ec, W_init_h, Hc, l_h, Hc, b_init_h, Ec, 0);
    gemm_f32<<<dim3(Bc / 64, Hc / 64), blk, 0, stream>>>(l_mean, Ec, W_init_c, Hc, l_c, Hc, b_init_c, Ec, 0);
    gemm_f32<<<dim3((Bc * Lc) / 64, Hc / 64), blk, 0, stream>>>(feats, Ec, U_a, Hc, l_keys, Hc, b_ua, Ec, 0);
    for (int t = 0; t < Tc; ++t) {
        gemm_f32<<<dim3(Bc / 64, Hc / 64), blk, 0, stream>>>(l_h, Hc, W_a, Hc, l_q, Hc, b_a, Hc, 0);
        att_scores<<<dim3((Bc * Lc) / 4), blk, 0, stream>>>(l_q, Hc, l_keys, V_a, b_va, l_e);
        softmax_L<<<dim3(Bc), blk, 0, stream>>>(l_e);
        z_kernel<<<dim3(Bc, 2), blk, 0, stream>>>(l_e, feats, l_z);
        gemm_f32<<<dim3(Bc / 64, Ec / 64), blk, 0, stream>>>(l_h, Hc, W_beta, Ec, l_sb, Ec, b_beta, Hc, 0);
        ctx_build<<<dim3(Bc, 4), blk, 0, stream>>>(l_z, l_sb, caption, emb, l_ctx, t);
        gemm_f32<<<dim3(Bc / 64, (4 * Hc) / 64), blk, 0, stream>>>(l_ctx, 2 * Ec, W_lstm, 4 * Hc, l_gates, 4 * Hc, b_lstm, 2 * Ec, 0);
        gemm_f32<<<dim3(Bc / 64, (4 * Hc) / 64), blk, 0, stream>>>(l_h, Hc, U_lstm, 4 * Hc, l_gates, 4 * Hc, nullptr, Hc, 1);
        lstm_elem<<<dim3((Bc * Hc) / 256), blk, 0, stream>>>(l_gates, l_h, l_c, Hc);
        gemm_f32<<<dim3(Bc / 64, Vc / 64), blk, 0, stream>>>(l_h, Hc, W_out, Vc, out + (size_t)t * Vc, Tc * Vc, b_out, Hc, 0);
        softmax_V<<<dim3(Bc), dim3(1024), 0, stream>>>(out, t);
    }
}